// Round 9
// baseline (251.139 us; speedup 1.0000x reference)
//
#include <hip/hip_runtime.h>
#include <hip/hip_bf16.h>
#include <math.h>

// GNNLayer: B=4,T=4096,D=128,H=4,DH=32,FF=256
// bf16 MFMA (16x16x32) everywhere, fp32 accum, fp32 LN/residual/bias.
// R9: R5's proven softmax machinery (__expf + manual f2bf pack + manual l +
//     shuffle epilogue) with ONE structural change: 32 queries/wave (two
//     16-q tiles sharing each K/V fragment load). cvtpk inline asm RETIRED:
//     R7/R8 bisection shows cvtpk fed by short exp sequences corrupts lanes
//     (TRANS-op hazard not honored for inline-asm consumers).

#define B_ 4
#define T_ 4096
#define D_ 128
#define H_ 4
#define DH_ 32
#define FF_ 256
#define M_ (B_*T_)

typedef unsigned short u16;
typedef __attribute__((ext_vector_type(8))) short bf16x8;
typedef __attribute__((ext_vector_type(4))) float f32x4;
typedef __attribute__((ext_vector_type(4))) u16 u16x4;

// ---- workspace layout (bytes, 256-aligned) ----
constexpr size_t OFF_FLAG  = 0;     // int flag @0, float kmax2[16] @64
constexpr size_t OFF_MASKW = 256;                      // u32[T][T/32] = 2 MB
constexpr size_t OFF_XB    = OFF_MASKW + 2097152;      // bf16 x        4 MB
constexpr size_t OFF_WQKVT = OFF_XB    + 4194304;      // bf16 [384][128]
constexpr size_t OFF_WOT   = OFF_WQKVT + 98304;        // bf16 [128][128]
constexpr size_t OFF_W1T   = OFF_WOT   + 32768;        // bf16 [256][128]
constexpr size_t OFF_W2T   = OFF_W1T   + 65536;        // bf16 [128][256]
constexpr size_t OFF_QW    = OFF_W2T   + 65536;        // bf16 [16][T][32] (q, pre-scaled 1/sqrt(DH))
constexpr size_t OFF_KW    = OFF_QW    + 4194304;      // bf16 [16][T*32] fragment-major
constexpr size_t OFF_VT    = OFF_KW    + 4194304;      // bf16 [16][T*32] fragment-major v^T
constexpr size_t OFF_AO    = OFF_VT    + 4194304;      // bf16 attn out [M][128]
constexpr size_t OFF_Y32   = OFF_AO    + 4194304;      // f32 y (post-LN1) [M][128]
constexpr size_t OFF_YB    = OFF_Y32   + 8388608;      // bf16 y
constexpr size_t OFF_HB    = OFF_YB    + 4194304;      // bf16 gelu(ff1) [M][256]

__device__ __forceinline__ u16 f2bf(float f){
  unsigned u = __float_as_uint(f);
  u += 0x7FFFu + ((u >> 16) & 1u);
  return (u16)(u >> 16);
}

__device__ __forceinline__ float bf2f(u16 b){
  return __uint_as_float((unsigned)b << 16);
}

// frag loader (row-major source): p = base + row*stride + k0 + 4*(lane>>4)
__device__ __forceinline__ bf16x8 load_frag(const u16* p){
  union { bf16x8 v; uint2 u[2]; } f;
  f.u[0] = *(const uint2*)(p);
  f.u[1] = *(const uint2*)(p + 16);
  return f.v;
}

// ---- mask dtype detection + kmax2 zeroing ----
__global__ void k_detect(const unsigned* m, int* flag, float* kmax2){
  if (threadIdx.x < 16) kmax2[threadIdx.x] = 0.f;
  __shared__ int s_i32, s_f32;
  if (threadIdx.x == 0){ s_i32 = 1; s_f32 = 1; }
  __syncthreads();
  int li = 1, lf = 1;
  for (int i = threadIdx.x; i < 16384; i += 256){
    unsigned w = m[i];
    li &= (w <= 1u);
    lf &= (w == 0u || w == 0x3F800000u);
  }
  if (!li) atomicAnd(&s_i32, 0);
  if (!lf) atomicAnd(&s_f32, 0);
  __syncthreads();
  if (threadIdx.x == 0) *flag = (s_i32 | s_f32);
}

// pack (adj | eye) into bits: mw[i*128 + j/32] bit (j%32)
__global__ void k_pack(const void* mask, const int* flag, unsigned* mw){
  int idx = blockIdx.x*256 + threadIdx.x;   // word index, T*T/32 total
  int i = idx >> 7, wj = idx & 127;
  unsigned w = 0;
  if (*flag){
    const unsigned* p = (const unsigned*)mask + (size_t)i*T_ + wj*32;
    #pragma unroll
    for (int c = 0; c < 32; c++) w |= (p[c] != 0u ? 1u : 0u) << c;
  } else {
    const unsigned char* p = (const unsigned char*)mask + (size_t)i*T_ + wj*32;
    #pragma unroll
    for (int c = 0; c < 32; c++) w |= (p[c] ? 1u : 0u) << c;
  }
  if ((i >> 5) == wj) w |= 1u << (i & 31);
  mw[idx] = w;
}

__global__ void k_conv_x(const float* x, u16* xb){
  int i = (blockIdx.x*256 + threadIdx.x)*4;
  float4 v = *(const float4*)(x + i);
  u16x4 o = { f2bf(v.x), f2bf(v.y), f2bf(v.z), f2bf(v.w) };
  *(u16x4*)(xb + i) = o;
}

// weights -> bf16, transposed [N][K]
__global__ void k_conv_w(const float* Wq, const float* Wk, const float* Wv, const float* Wo,
                         const float* W1, const float* W2,
                         u16* wqkvt, u16* wot, u16* w1t, u16* w2t){
  int idx = blockIdx.x*256 + threadIdx.x;
  if (idx < 49152){                      // wqkvt[n<384][k<128]
    int n = idx >> 7, k = idx & 127;
    float v = (n < 128) ? Wq[k*128 + n] : (n < 256 ? Wk[k*128 + (n-128)] : Wv[k*128 + (n-256)]);
    wqkvt[idx] = f2bf(v);
  } else if (idx < 65536){               // wot[n<128][k<128]
    int j = idx - 49152, n = j >> 7, k = j & 127;
    wot[j] = f2bf(Wo[k*128 + n]);
  } else if (idx < 98304){               // w1t[n<256][k<128]
    int j = idx - 65536, n = j >> 7, k = j & 127;
    w1t[j] = f2bf(W1[k*256 + n]);
  } else if (idx < 131072){              // w2t[n<128][k<256]
    int j = idx - 98304, n = j >> 8, k = j & 255;
    w2t[j] = f2bf(W2[k*128 + n]);
  }
}

// QKV GEMM: grid 1024 (16 rows each), 4 waves x 96 cols. q scaled by 1/sqrt(32).
// K and V written in fragment-major layouts.
__global__ __launch_bounds__(256) void k_qkv(const u16* xb, const u16* wt,
    const float* bq, const float* bk, const float* bv,
    u16* qw, u16* kw, u16* vt){
  const int wv = threadIdx.x >> 6, lane = threadIdx.x & 63;
  const int r15 = lane & 15, g = lane >> 4;
  const int m0 = blockIdx.x * 16;
  f32x4 acc[6] = {};
  const u16* ar = xb + (size_t)(m0 + r15)*D_ + 4*g;
  #pragma unroll
  for (int kk = 0; kk < D_; kk += 32){
    bf16x8 af = load_frag(ar + kk);
    #pragma unroll
    for (int nf = 0; nf < 6; nf++){
      const u16* br = wt + (size_t)(wv*96 + nf*16 + r15)*D_ + kk + 4*g;
      acc[nf] = __builtin_amdgcn_mfma_f32_16x16x32_bf16(af, load_frag(br), acc[nf], 0, 0, 0);
    }
  }
  const int b = m0 >> 12, t0 = m0 & (T_-1);
  #pragma unroll
  for (int nf = 0; nf < 6; nf++){
    int ncol = wv*96 + nf*16 + r15;
    if (ncol < 128){
      int h = ncol >> 5, d = ncol & 31;
      float bias = bq[ncol];
      u16* dst = qw + ((size_t)(b*H_ + h)*T_)*DH_;
      #pragma unroll
      for (int rr = 0; rr < 4; rr++){
        int t = t0 + 4*g + rr;
        dst[(size_t)t*DH_ + d] = f2bf((acc[nf][rr] + bias) * 0.17677669529663687f);  // 1/sqrt(32)
      }
    } else if (ncol < 256){
      // K fragment-major: S_k(t,d) = (t>>4)*512 + ((d>>2)&3)*128 + (t&15)*8 + 4*(d>>4) + (d&3)
      int c = ncol - 128, h = c >> 5, d = c & 31;
      float bias = bk[c];
      u16* dst = kw + (size_t)(b*H_ + h)*T_*DH_
               + (size_t)(t0 >> 4)*512 + (size_t)((d >> 2) & 3)*128 + 4*(d >> 4) + (d & 3);
      #pragma unroll
      for (int rr = 0; rr < 4; rr++)
        dst[(4*g + rr)*8] = f2bf(acc[nf][rr] + bias);   // t&15 = 4g+rr
    } else {
      // V fragment-major: key t=t0+4g+rr, fixed d. base + rr are consecutive elems.
      int c = ncol - 256, h = c >> 5, d = c & 31;
      float bias = bv[c];
      int t = t0 + 4*g;
      int tin = t & 31;
      u16x4 v4;
      #pragma unroll
      for (int rr = 0; rr < 4; rr++) v4[rr] = f2bf(acc[nf][rr] + bias);
      u16* dst = vt + (size_t)(b*H_ + h)*T_*DH_
               + (size_t)(t >> 5)*1024 + (size_t)(d >> 4)*512
               + (size_t)(g*16 + (d & 15))*8 + 4*(tin >> 4);
      *(u16x4*)dst = v4;
    }
  }
}

// max_j ||k_j||^2 per (b,h) -> kmax2[bh]. Swizzle-aware gather (4 x 16B per key).
__global__ void k_knorm(const u16* kw, float* kmax2){
  const int bh = blockIdx.x, tid = threadIdx.x;
  const u16* kp = kw + (size_t)bh*T_*DH_;
  float mx = 0.f;
  for (int t = tid; t < T_; t += 256){
    const u16* base = kp + (size_t)(t >> 4)*512 + (t & 15)*8;
    float s = 0.f;
    #pragma unroll
    for (int g = 0; g < 4; g++){
      union { uint4 u4; u16 e[8]; } v;
      v.u4 = *(const uint4*)(base + g*128);
      #pragma unroll
      for (int j = 0; j < 8; j++){ float f = bf2f(v.e[j]); s += f*f; }
    }
    mx = fmaxf(mx, s);
  }
  #pragma unroll
  for (int d = 1; d < 64; d <<= 1) mx = fmaxf(mx, __shfl_xor(mx, d));
  if ((tid & 63) == 0) atomicMax((unsigned*)(kmax2 + bh), __float_as_uint(mx));
}

// Bounded-softmax attention (__expf). Swapped QK^T; shift+mask in C-init.
// 32 queries/wave (two 16-q tiles A,B sharing each K/V fragment load).
// grid = BH(16) * T/128 = 512; 4 waves/block (128 q/block). XCD swizzle.
__global__ __launch_bounds__(256, 4) void k_attn9(const u16* qw, const u16* kw, const u16* vt,
    const unsigned* mw, const float* kmax2, u16* ao){
  const int wg = (blockIdx.x & 7)*64 + (blockIdx.x >> 3);   // 8 XCDs x 64 contiguous
  const int wv = threadIdx.x >> 6, lane = threadIdx.x & 63;
  const int r15 = lane & 15, g = lane >> 4;
  const int bh = wg >> 5;
  const int q0 = (wg & 31)*128 + wv*32;
  const u16* qp = qw + (size_t)bh*T_*DH_;
  const u16* kl = kw + (size_t)bh*T_*DH_ + lane*8;   // fragment-major, lane offset folded
  const u16* vl = vt + (size_t)bh*T_*DH_ + lane*8;
  const unsigned* mrowA = mw + (size_t)(q0 + r15)*(T_/32);
  const unsigned* mrowB = mrowA + 16*(T_/32);
  const bf16x8 qfA = load_frag(qp + (size_t)(q0 + r15)*DH_ + 4*g);
  const bf16x8 qfB = load_frag(qp + (size_t)(q0 + 16 + r15)*DH_ + 4*g);
  // ||q||^2 per lane's query
  float nA = 0.f, nB = 0.f;
  #pragma unroll
  for (int j = 0; j < 8; j++){
    float fA = bf2f((u16)qfA[j]), fB = bf2f((u16)qfB[j]);
    nA += fA*fA; nB += fB*fB;
  }
  nA += __shfl_xor(nA, 16); nA += __shfl_xor(nA, 32);
  nB += __shfl_xor(nB, 16); nB += __shfl_xor(nB, 32);
  const float km = kmax2[bh];
  const float bndA = sqrtf(nA * km) * 1.0001f + 1e-6f;   // >= max_j |q.k_j|
  const float bndB = sqrtf(nB * km) * 1.0001f + 1e-6f;
  f32x4 oA0 = {}, oA1 = {}, oB0 = {}, oB1 = {};
  float lA = 0.f, lB = 0.f;
  for (int jb4 = 0; jb4 < T_; jb4 += 128){
    const uint4 wA4 = *(const uint4*)(mrowA + (jb4 >> 5));
    const uint4 wB4 = *(const uint4*)(mrowB + (jb4 >> 5));
    #pragma unroll
    for (int ji = 0; ji < 4; ji++){
      const int jb = jb4 + ji*32;
      const unsigned uA = ((const unsigned*)&wA4)[ji] >> (4*g);
      const unsigned uB = ((const unsigned*)&wB4)[ji] >> (4*g);
      bf16x8 kf0 = *(const bf16x8*)(kl + (size_t)(jb >> 4)*512);
      bf16x8 kf1 = *(const bf16x8*)(kl + (size_t)((jb >> 4) + 1)*512);
      bf16x8 vf0 = *(const bf16x8*)(vl + (size_t)(jb >> 5)*1024);
      bf16x8 vf1 = *(const bf16x8*)(vl + (size_t)(jb >> 5)*1024 + 512);
      f32x4 cA0, cA1, cB0, cB1;   // -bnd if masked-in else -1e30 (exp -> 0)
      #pragma unroll
      for (int rr = 0; rr < 4; rr++){
        cA0[rr] = ((uA >> rr) & 1u)        ? -bndA : -1e30f;
        cA1[rr] = ((uA >> (16 + rr)) & 1u) ? -bndA : -1e30f;
        cB0[rr] = ((uB >> rr) & 1u)        ? -bndB : -1e30f;
        cB1[rr] = ((uB >> (16 + rr)) & 1u) ? -bndB : -1e30f;
      }
      f32x4 sA0 = __builtin_amdgcn_mfma_f32_16x16x32_bf16(kf0, qfA, cA0, 0, 0, 0);
      f32x4 sA1 = __builtin_amdgcn_mfma_f32_16x16x32_bf16(kf1, qfA, cA1, 0, 0, 0);
      f32x4 sB0 = __builtin_amdgcn_mfma_f32_16x16x32_bf16(kf0, qfB, cB0, 0, 0, 0);
      f32x4 sB1 = __builtin_amdgcn_mfma_f32_16x16x32_bf16(kf1, qfB, cB1, 0, 0, 0);
      float pA0[4], pA1[4], pB0[4], pB1[4];
      #pragma unroll
      for (int rr = 0; rr < 4; rr++){
        pA0[rr] = __expf(sA0[rr]);  pA1[rr] = __expf(sA1[rr]);
        pB0[rr] = __expf(sB0[rr]);  pB1[rr] = __expf(sB1[rr]);
        lA += pA0[rr] + pA1[rr];
        lB += pB0[rr] + pB1[rr];
      }
      union { bf16x8 v; u16 e[8]; } pfA, pfB;
      #pragma unroll
      for (int j = 0; j < 4; j++){
        pfA.e[j] = f2bf(pA0[j]); pfA.e[4+j] = f2bf(pA1[j]);
        pfB.e[j] = f2bf(pB0[j]); pfB.e[4+j] = f2bf(pB1[j]);
      }
      oA0 = __builtin_amdgcn_mfma_f32_16x16x32_bf16(pfA.v, vf0, oA0, 0, 0, 0);
      oA1 = __builtin_amdgcn_mfma_f32_16x16x32_bf16(pfA.v, vf1, oA1, 0, 0, 0);
      oB0 = __builtin_amdgcn_mfma_f32_16x16x32_bf16(pfB.v, vf0, oB0, 0, 0, 0);
      oB1 = __builtin_amdgcn_mfma_f32_16x16x32_bf16(pfB.v, vf1, oB1, 0, 0, 0);
    }
  }
  lA += __shfl_xor(lA, 16); lA += __shfl_xor(lA, 32);
  lB += __shfl_xor(lB, 16); lB += __shfl_xor(lB, 32);
  const int b = bh >> 2, h = bh & 3;
  #pragma unroll
  for (int rr = 0; rr < 4; rr++){
    float liA = __shfl(lA, 4*g + rr);   // O rows are queries 4g+rr
    float invA = liA > 0.f ? 1.f/liA : 0.f;
    size_t rowA = (size_t)(b*T_ + q0 + 4*g + rr)*D_;
    ao[rowA + h*DH_ + r15]      = f2bf(oA0[rr]*invA);
    ao[rowA + h*DH_ + 16 + r15] = f2bf(oA1[rr]*invA);
    float liB = __shfl(lB, 4*g + rr);
    float invB = liB > 0.f ? 1.f/liB : 0.f;
    size_t rowB = (size_t)(b*T_ + q0 + 16 + 4*g + rr)*D_;
    ao[rowB + h*DH_ + r15]      = f2bf(oB0[rr]*invB);
    ao[rowB + h*DH_ + 16 + r15] = f2bf(oB1[rr]*invB);
  }
}

// out-proj + residual + LN1. grid 256, 64 rows/block.
__global__ __launch_bounds__(256) void k_proj_ln1(const u16* ao, const u16* wot, const float* bo,
    const float* x, const float* g1, const float* be1, float* y32, u16* yb){
  const int wv = threadIdx.x >> 6, lane = threadIdx.x & 63;
  const int r15 = lane & 15, g = lane >> 4;
  const int m0 = blockIdx.x*64 + wv*16;
  f32x4 acc[8] = {};
  const u16* ar = ao + (size_t)(m0 + r15)*D_ + 4*g;
  #pragma unroll
  for (int kk = 0; kk < D_; kk += 32){
    bf16x8 af = load_frag(ar + kk);
    #pragma unroll
    for (int nf = 0; nf < 8; nf++)
      acc[nf] = __builtin_amdgcn_mfma_f32_16x16x32_bf16(af,
          load_frag(wot + (size_t)(nf*16 + r15)*D_ + kk + 4*g), acc[nf], 0, 0, 0);
  }
  #pragma unroll
  for (int rr = 0; rr < 4; rr++){
    const size_t m = m0 + 4*g + rr;
    float v[8], s1 = 0.f, s2 = 0.f;
    #pragma unroll
    for (int nf = 0; nf < 8; nf++){
      int col = nf*16 + r15;
      float t = acc[nf][rr] + bo[col] + x[m*D_ + col];
      v[nf] = t; s1 += t; s2 += t*t;
    }
    #pragma unroll
    for (int d = 1; d < 16; d <<= 1){ s1 += __shfl_xor(s1, d); s2 += __shfl_xor(s2, d); }
    float mu = s1 * (1.f/D_);
    float var = fmaxf(s2 * (1.f/D_) - mu*mu, 0.f);
    float inv = rsqrtf(var + 1e-5f);
    #pragma unroll
    for (int nf = 0; nf < 8; nf++){
      int col = nf*16 + r15;
      float o = (v[nf]-mu)*inv*g1[col] + be1[col];
      y32[m*D_ + col] = o;
      yb[m*D_ + col] = f2bf(o);
    }
  }
}

// FF1 + exact GELU. grid 1024 (16 rows), 4 waves x 64 cols.
__global__ __launch_bounds__(256) void k_ff1(const u16* yb, const u16* w1t, const float* bf1, u16* hb){
  const int wv = threadIdx.x >> 6, lane = threadIdx.x & 63;
  const int r15 = lane & 15, g = lane >> 4;
  const int m0 = blockIdx.x*16;
  const int n0w = wv*64;
  f32x4 acc[4] = {};
  const u16* ar = yb + (size_t)(m0 + r15)*D_ + 4*g;
  #pragma unroll
  for (int kk = 0; kk < D_; kk += 32){
    bf16x8 af = load_frag(ar + kk);
    #pragma unroll
    for (int nf = 0; nf < 4; nf++)
      acc[nf] = __builtin_amdgcn_mfma_f32_16x16x32_bf16(af,
          load_frag(w1t + (size_t)(n0w + nf*16 + r15)*D_ + kk + 4*g), acc[nf], 0, 0, 0);
  }
  #pragma unroll
  for (int nf = 0; nf < 4; nf++){
    int col = n0w + nf*16 + r15;
    float bias = bf1[col];
    #pragma unroll
    for (int rr = 0; rr < 4; rr++){
      float vv = acc[nf][rr] + bias;
      float gl = 0.5f*vv*(1.f + erff(vv*0.70710678118654752f));
      hb[(size_t)(m0 + 4*g + rr)*FF_ + col] = f2bf(gl);
    }
  }
}

// FF2 + residual + LN2 -> d_out (fp32). grid 256, 64 rows/block.
__global__ __launch_bounds__(256) void k_ff2_ln2(const u16* hb, const u16* w2t, const float* b2,
    const float* y32, const float* g2, const float* be2, float* out){
  const int wv = threadIdx.x >> 6, lane = threadIdx.x & 63;
  const int r15 = lane & 15, g = lane >> 4;
  const int m0 = blockIdx.x*64 + wv*16;
  f32x4 acc[8] = {};
  const u16* ar = hb + (size_t)(m0 + r15)*FF_ + 4*g;
  #pragma unroll
  for (int kk = 0; kk < FF_; kk += 32){
    bf16x8 af = load_frag(ar + kk);
    #pragma unroll
    for (int nf = 0; nf < 8; nf++)
      acc[nf] = __builtin_amdgcn_mfma_f32_16x16x32_bf16(af,
          load_frag(w2t + (size_t)(nf*16 + r15)*FF_ + kk + 4*g), acc[nf], 0, 0, 0);
  }
  #pragma unroll
  for (int rr = 0; rr < 4; rr++){
    const size_t m = m0 + 4*g + rr;
    float v[8], s1 = 0.f, s2 = 0.f;
    #pragma unroll
    for (int nf = 0; nf < 8; nf++){
      int col = nf*16 + r15;
      float t = acc[nf][rr] + b2[col] + y32[m*D_ + col];
      v[nf] = t; s1 += t; s2 += t*t;
    }
    #pragma unroll
    for (int d = 1; d < 16; d <<= 1){ s1 += __shfl_xor(s1, d); s2 += __shfl_xor(s2, d); }
    float mu = s1 * (1.f/D_);
    float var = fmaxf(s2 * (1.f/D_) - mu*mu, 0.f);
    float inv = rsqrtf(var + 1e-5f);
    #pragma unroll
    for (int nf = 0; nf < 8; nf++){
      int col = nf*16 + r15;
      out[m*D_ + col] = (v[nf]-mu)*inv*g2[col] + be2[col];
    }
  }
}

extern "C" void kernel_launch(void* const* d_in, const int* in_sizes, int n_in,
                              void* d_out, int out_size, void* d_ws, size_t ws_size,
                              hipStream_t stream){
  const float* x   = (const float*)d_in[0];
  const void*  msk = d_in[1];
  const float* Wq = (const float*)d_in[2];  const float* bq  = (const float*)d_in[3];
  const float* Wk = (const float*)d_in[4];  const float* bk  = (const float*)d_in[5];
  const float* Wv = (const float*)d_in[6];  const float* bv  = (const float*)d_in[7];
  const float* Wo = (const float*)d_in[8];  const float* bo  = (const float*)d_in[9];
  const float* g1 = (const float*)d_in[10]; const float* be1 = (const float*)d_in[11];
  const float* W1 = (const float*)d_in[12]; const float* bf1 = (const float*)d_in[13];
  const float* W2 = (const float*)d_in[14]; const float* b2  = (const float*)d_in[15];
  const float* g2 = (const float*)d_in[16]; const float* be2 = (const float*)d_in[17];

  char* ws = (char*)d_ws;
  int*      flag  = (int*)     (ws + OFF_FLAG);
  float*    kmax2 = (float*)   (ws + OFF_FLAG + 64);
  unsigned* mw    = (unsigned*)(ws + OFF_MASKW);
  u16* xb    = (u16*)(ws + OFF_XB);
  u16* wqkvt = (u16*)(ws + OFF_WQKVT);
  u16* wot   = (u16*)(ws + OFF_WOT);
  u16* w1t   = (u16*)(ws + OFF_W1T);
  u16* w2t   = (u16*)(ws + OFF_W2T);
  u16* qw    = (u16*)(ws + OFF_QW);
  u16* kw    = (u16*)(ws + OFF_KW);
  u16* vt    = (u16*)(ws + OFF_VT);
  u16* ao    = (u16*)(ws + OFF_AO);
  float* y32 = (float*)(ws + OFF_Y32);
  u16* yb    = (u16*)(ws + OFF_YB);
  u16* hb    = (u16*)(ws + OFF_HB);

  k_detect<<<1, 256, 0, stream>>>((const unsigned*)msk, flag, kmax2);
  k_pack  <<<(T_*T_/32)/256, 256, 0, stream>>>(msk, flag, mw);
  k_conv_x<<<(M_*D_/4)/256, 256, 0, stream>>>(x, xb);
  k_conv_w<<<131072/256, 256, 0, stream>>>(Wq, Wk, Wv, Wo, W1, W2, wqkvt, wot, w1t, w2t);
  k_qkv   <<<M_/16, 256, 0, stream>>>(xb, wqkvt, bq, bk, bv, qw, kw, vt);
  k_knorm <<<B_*H_, 256, 0, stream>>>(kw, kmax2);
  k_attn9 <<<(B_*H_)*(T_/128), 256, 0, stream>>>(qw, kw, vt, mw, kmax2, ao);
  k_proj_ln1<<<M_/64, 256, 0, stream>>>(ao, wot, bo, x, g1, be1, y32, yb);
  k_ff1   <<<M_/16, 256, 0, stream>>>(yb, w1t, bf1, hb);
  k_ff2_ln2<<<M_/64, 256, 0, stream>>>(hb, w2t, b2, y32, g2, be2, (float*)d_out);
}

// Round 10
// 221.722 us; speedup vs baseline: 1.1327x; 1.1327x over previous
//
#include <hip/hip_runtime.h>
#include <hip/hip_bf16.h>
#include <math.h>

// GNNLayer: B=4,T=4096,D=128,H=4,DH=32,FF=256
// bf16 MFMA (16x16x32) everywhere, fp32 accum, fp32 LN/residual/bias.
// R10: R5 base (16q/wave, grid 1024 - R9 showed 32q/wave halves occupancy and
//      loses) + two PROVEN VALU cuts:
//      (a) ones-column MFMA denominator (R6-proven): kills l-adds + epilogue shuffles
//      (b) pack via __float22bfloat162_rn (compiler-generated cvt_pk, NOT inline
//          asm - avoids the R7/R8 TRANS-hazard-vs-asm failure mode)

#define B_ 4
#define T_ 4096
#define D_ 128
#define H_ 4
#define DH_ 32
#define FF_ 256
#define M_ (B_*T_)

typedef unsigned short u16;
typedef __attribute__((ext_vector_type(8))) short bf16x8;
typedef __attribute__((ext_vector_type(4))) float f32x4;
typedef __attribute__((ext_vector_type(4))) u16 u16x4;

// ---- workspace layout (bytes, 256-aligned) ----
constexpr size_t OFF_FLAG  = 0;     // int flag @0, float kmax2[16] @64
constexpr size_t OFF_MASKW = 256;                      // u32[T][T/32] = 2 MB
constexpr size_t OFF_XB    = OFF_MASKW + 2097152;      // bf16 x        4 MB
constexpr size_t OFF_WQKVT = OFF_XB    + 4194304;      // bf16 [384][128]
constexpr size_t OFF_WOT   = OFF_WQKVT + 98304;        // bf16 [128][128]
constexpr size_t OFF_W1T   = OFF_WOT   + 32768;        // bf16 [256][128]
constexpr size_t OFF_W2T   = OFF_W1T   + 65536;        // bf16 [128][256]
constexpr size_t OFF_QW    = OFF_W2T   + 65536;        // bf16 [16][T][32] (q, pre-scaled 1/sqrt(DH))
constexpr size_t OFF_KW    = OFF_QW    + 4194304;      // bf16 [16][T*32] fragment-major
constexpr size_t OFF_VT    = OFF_KW    + 4194304;      // bf16 [16][T*32] fragment-major v^T
constexpr size_t OFF_AO    = OFF_VT    + 4194304;      // bf16 attn out [M][128]
constexpr size_t OFF_Y32   = OFF_AO    + 4194304;      // f32 y (post-LN1) [M][128]
constexpr size_t OFF_YB    = OFF_Y32   + 8388608;      // bf16 y
constexpr size_t OFF_HB    = OFF_YB    + 4194304;      // bf16 gelu(ff1) [M][256]

__device__ __forceinline__ u16 f2bf(float f){
  unsigned u = __float_as_uint(f);
  u += 0x7FFFu + ((u >> 16) & 1u);
  return (u16)(u >> 16);
}

__device__ __forceinline__ float bf2f(u16 b){
  return __uint_as_float((unsigned)b << 16);
}

// frag loader (row-major source): p = base + row*stride + k0 + 4*(lane>>4)
__device__ __forceinline__ bf16x8 load_frag(const u16* p){
  union { bf16x8 v; uint2 u[2]; } f;
  f.u[0] = *(const uint2*)(p);
  f.u[1] = *(const uint2*)(p + 16);
  return f.v;
}

// ---- mask dtype detection + kmax2 zeroing ----
__global__ void k_detect(const unsigned* m, int* flag, float* kmax2){
  if (threadIdx.x < 16) kmax2[threadIdx.x] = 0.f;
  __shared__ int s_i32, s_f32;
  if (threadIdx.x == 0){ s_i32 = 1; s_f32 = 1; }
  __syncthreads();
  int li = 1, lf = 1;
  for (int i = threadIdx.x; i < 16384; i += 256){
    unsigned w = m[i];
    li &= (w <= 1u);
    lf &= (w == 0u || w == 0x3F800000u);
  }
  if (!li) atomicAnd(&s_i32, 0);
  if (!lf) atomicAnd(&s_f32, 0);
  __syncthreads();
  if (threadIdx.x == 0) *flag = (s_i32 | s_f32);
}

// pack (adj | eye) into bits: mw[i*128 + j/32] bit (j%32)
__global__ void k_pack(const void* mask, const int* flag, unsigned* mw){
  int idx = blockIdx.x*256 + threadIdx.x;   // word index, T*T/32 total
  int i = idx >> 7, wj = idx & 127;
  unsigned w = 0;
  if (*flag){
    const unsigned* p = (const unsigned*)mask + (size_t)i*T_ + wj*32;
    #pragma unroll
    for (int c = 0; c < 32; c++) w |= (p[c] != 0u ? 1u : 0u) << c;
  } else {
    const unsigned char* p = (const unsigned char*)mask + (size_t)i*T_ + wj*32;
    #pragma unroll
    for (int c = 0; c < 32; c++) w |= (p[c] ? 1u : 0u) << c;
  }
  if ((i >> 5) == wj) w |= 1u << (i & 31);
  mw[idx] = w;
}

__global__ void k_conv_x(const float* x, u16* xb){
  int i = (blockIdx.x*256 + threadIdx.x)*4;
  float4 v = *(const float4*)(x + i);
  u16x4 o = { f2bf(v.x), f2bf(v.y), f2bf(v.z), f2bf(v.w) };
  *(u16x4*)(xb + i) = o;
}

// weights -> bf16, transposed [N][K]
__global__ void k_conv_w(const float* Wq, const float* Wk, const float* Wv, const float* Wo,
                         const float* W1, const float* W2,
                         u16* wqkvt, u16* wot, u16* w1t, u16* w2t){
  int idx = blockIdx.x*256 + threadIdx.x;
  if (idx < 49152){                      // wqkvt[n<384][k<128]
    int n = idx >> 7, k = idx & 127;
    float v = (n < 128) ? Wq[k*128 + n] : (n < 256 ? Wk[k*128 + (n-128)] : Wv[k*128 + (n-256)]);
    wqkvt[idx] = f2bf(v);
  } else if (idx < 65536){               // wot[n<128][k<128]
    int j = idx - 49152, n = j >> 7, k = j & 127;
    wot[j] = f2bf(Wo[k*128 + n]);
  } else if (idx < 98304){               // w1t[n<256][k<128]
    int j = idx - 65536, n = j >> 7, k = j & 127;
    w1t[j] = f2bf(W1[k*256 + n]);
  } else if (idx < 131072){              // w2t[n<128][k<256]
    int j = idx - 98304, n = j >> 8, k = j & 255;
    w2t[j] = f2bf(W2[k*128 + n]);
  }
}

// QKV GEMM: grid 1024 (16 rows each), 4 waves x 96 cols. q scaled by 1/sqrt(32).
// K and V written in fragment-major layouts.
__global__ __launch_bounds__(256) void k_qkv(const u16* xb, const u16* wt,
    const float* bq, const float* bk, const float* bv,
    u16* qw, u16* kw, u16* vt){
  const int wv = threadIdx.x >> 6, lane = threadIdx.x & 63;
  const int r15 = lane & 15, g = lane >> 4;
  const int m0 = blockIdx.x * 16;
  f32x4 acc[6] = {};
  const u16* ar = xb + (size_t)(m0 + r15)*D_ + 4*g;
  #pragma unroll
  for (int kk = 0; kk < D_; kk += 32){
    bf16x8 af = load_frag(ar + kk);
    #pragma unroll
    for (int nf = 0; nf < 6; nf++){
      const u16* br = wt + (size_t)(wv*96 + nf*16 + r15)*D_ + kk + 4*g;
      acc[nf] = __builtin_amdgcn_mfma_f32_16x16x32_bf16(af, load_frag(br), acc[nf], 0, 0, 0);
    }
  }
  const int b = m0 >> 12, t0 = m0 & (T_-1);
  #pragma unroll
  for (int nf = 0; nf < 6; nf++){
    int ncol = wv*96 + nf*16 + r15;
    if (ncol < 128){
      int h = ncol >> 5, d = ncol & 31;
      float bias = bq[ncol];
      u16* dst = qw + ((size_t)(b*H_ + h)*T_)*DH_;
      #pragma unroll
      for (int rr = 0; rr < 4; rr++){
        int t = t0 + 4*g + rr;
        dst[(size_t)t*DH_ + d] = f2bf((acc[nf][rr] + bias) * 0.17677669529663687f);  // 1/sqrt(32)
      }
    } else if (ncol < 256){
      // K fragment-major: S_k(t,d) = (t>>4)*512 + ((d>>2)&3)*128 + (t&15)*8 + 4*(d>>4) + (d&3)
      int c = ncol - 128, h = c >> 5, d = c & 31;
      float bias = bk[c];
      u16* dst = kw + (size_t)(b*H_ + h)*T_*DH_
               + (size_t)(t0 >> 4)*512 + (size_t)((d >> 2) & 3)*128 + 4*(d >> 4) + (d & 3);
      #pragma unroll
      for (int rr = 0; rr < 4; rr++)
        dst[(4*g + rr)*8] = f2bf(acc[nf][rr] + bias);   // t&15 = 4g+rr
    } else {
      // V fragment-major: key t=t0+4g+rr, fixed d. base + rr are consecutive elems.
      int c = ncol - 256, h = c >> 5, d = c & 31;
      float bias = bv[c];
      int t = t0 + 4*g;
      int tin = t & 31;
      u16x4 v4;
      #pragma unroll
      for (int rr = 0; rr < 4; rr++) v4[rr] = f2bf(acc[nf][rr] + bias);
      u16* dst = vt + (size_t)(b*H_ + h)*T_*DH_
               + (size_t)(t >> 5)*1024 + (size_t)(d >> 4)*512
               + (size_t)(g*16 + (d & 15))*8 + 4*(tin >> 4);
      *(u16x4*)dst = v4;
    }
  }
}

// max_j ||k_j||^2 per (b,h) -> kmax2[bh]. Swizzle-aware gather (4 x 16B per key).
__global__ void k_knorm(const u16* kw, float* kmax2){
  const int bh = blockIdx.x, tid = threadIdx.x;
  const u16* kp = kw + (size_t)bh*T_*DH_;
  float mx = 0.f;
  for (int t = tid; t < T_; t += 256){
    const u16* base = kp + (size_t)(t >> 4)*512 + (t & 15)*8;
    float s = 0.f;
    #pragma unroll
    for (int g = 0; g < 4; g++){
      union { uint4 u4; u16 e[8]; } v;
      v.u4 = *(const uint4*)(base + g*128);
      #pragma unroll
      for (int j = 0; j < 8; j++){ float f = bf2f(v.e[j]); s += f*f; }
    }
    mx = fmaxf(mx, s);
  }
  #pragma unroll
  for (int d = 1; d < 64; d <<= 1) mx = fmaxf(mx, __shfl_xor(mx, d));
  if ((tid & 63) == 0) atomicMax((unsigned*)(kmax2 + bh), __float_as_uint(mx));
}

// Bounded-softmax attention (__expf). Swapped QK^T; shift+mask in C-init.
// l via ones-column MFMA; P pack via __float22bfloat162_rn (compiler cvt_pk).
// grid = BH(16) * T/64 = 1024; 4 waves/block, 16 queries/wave. XCD swizzle.
__global__ __launch_bounds__(256, 4) void k_attn10(const u16* qw, const u16* kw, const u16* vt,
    const unsigned* mw, const float* kmax2, u16* ao){
  const int wg = (blockIdx.x & 7)*128 + (blockIdx.x >> 3);   // 8 XCDs x 128 contiguous
  const int wv = threadIdx.x >> 6, lane = threadIdx.x & 63;
  const int r15 = lane & 15, g = lane >> 4;
  const int bh = wg >> 6;
  const int q0 = (wg & 63)*64 + wv*16;
  const u16* qp = qw + (size_t)bh*T_*DH_;
  const u16* kl = kw + (size_t)bh*T_*DH_ + lane*8;   // fragment-major, lane offset folded
  const u16* vl = vt + (size_t)bh*T_*DH_ + lane*8;
  const unsigned* mrow = mw + (size_t)(q0 + r15)*(T_/32);
  const bf16x8 qf = load_frag(qp + (size_t)(q0 + r15)*DH_ + 4*g);
  // ||q||^2 for this lane's query (q0+r15)
  float n0 = 0.f;
  #pragma unroll
  for (int j = 0; j < 8; j++){ float f = bf2f((u16)qf[j]); n0 += f*f; }
  n0 += __shfl_xor(n0, 16); n0 += __shfl_xor(n0, 32);
  const float bnd = sqrtf(n0 * kmax2[bh]) * 1.0001f + 1e-6f;  // >= max_j |q.k_j|
  // all-ones bf16 fragment: B=1s makes every PV-style output column = row-sum(P)
  union { u16 e[8]; bf16x8 v; } ones;
  #pragma unroll
  for (int j = 0; j < 8; j++) ones.e[j] = 0x3F80;
  f32x4 o0 = {}, o1 = {}, ol = {};
  for (int jb4 = 0; jb4 < T_; jb4 += 128){
    const uint4 wv4 = *(const uint4*)(mrow + (jb4 >> 5));
    #pragma unroll
    for (int ji = 0; ji < 4; ji++){
      const int jb = jb4 + ji*32;
      const unsigned w = ((const unsigned*)&wv4)[ji];
      const unsigned u = w >> (4*g);
      bf16x8 kf0 = *(const bf16x8*)(kl + (size_t)(jb >> 4)*512);
      bf16x8 kf1 = *(const bf16x8*)(kl + (size_t)((jb >> 4) + 1)*512);
      bf16x8 vf0 = *(const bf16x8*)(vl + (size_t)(jb >> 5)*1024);
      bf16x8 vf1 = *(const bf16x8*)(vl + (size_t)(jb >> 5)*1024 + 512);
      f32x4 c0, c1;   // -bnd if masked-in else -1e30 (exp -> 0)
      #pragma unroll
      for (int rr = 0; rr < 4; rr++){
        c0[rr] = ((u >> rr) & 1u)        ? -bnd : -1e30f;
        c1[rr] = ((u >> (16 + rr)) & 1u) ? -bnd : -1e30f;
      }
      f32x4 s0 = __builtin_amdgcn_mfma_f32_16x16x32_bf16(kf0, qf, c0, 0, 0, 0);
      f32x4 s1 = __builtin_amdgcn_mfma_f32_16x16x32_bf16(kf1, qf, c1, 0, 0, 0);
      float p0[4], p1[4];
      #pragma unroll
      for (int rr = 0; rr < 4; rr++){
        p0[rr] = __expf(s0[rr]);     // native: v_mul(log2e) + v_exp (R5-proven)
        p1[rr] = __expf(s1[rr]);
      }
      // pack via compiler-generated v_cvt_pk_bf16_f32 (header function, hazards
      // owned by the compiler - inline-asm cvtpk after v_exp corrupted lanes R7/R8)
      union { bf16x8 v; __hip_bfloat162 h2[4]; } pf;
      pf.h2[0] = __float22bfloat162_rn(make_float2(p0[0], p0[1]));
      pf.h2[1] = __float22bfloat162_rn(make_float2(p0[2], p0[3]));
      pf.h2[2] = __float22bfloat162_rn(make_float2(p1[0], p1[1]));
      pf.h2[3] = __float22bfloat162_rn(make_float2(p1[2], p1[3]));
      o0 = __builtin_amdgcn_mfma_f32_16x16x32_bf16(pf.v, vf0, o0, 0, 0, 0);
      o1 = __builtin_amdgcn_mfma_f32_16x16x32_bf16(pf.v, vf1, o1, 0, 0, 0);
      ol = __builtin_amdgcn_mfma_f32_16x16x32_bf16(pf.v, ones.v, ol, 0, 0, 0);
    }
  }
  const int b = bh >> 2, h = bh & 3;
  #pragma unroll
  for (int rr = 0; rr < 4; rr++){
    float li = ol[rr];                  // l for query 4g+rr, present in every lane
    float inv = li > 0.f ? 1.f/li : 0.f;
    size_t row = (size_t)(b*T_ + q0 + 4*g + rr)*D_;
    ao[row + h*DH_ + r15]      = f2bf(o0[rr]*inv);
    ao[row + h*DH_ + 16 + r15] = f2bf(o1[rr]*inv);
  }
}

// out-proj + residual + LN1. grid 256, 64 rows/block.
__global__ __launch_bounds__(256) void k_proj_ln1(const u16* ao, const u16* wot, const float* bo,
    const float* x, const float* g1, const float* be1, float* y32, u16* yb){
  const int wv = threadIdx.x >> 6, lane = threadIdx.x & 63;
  const int r15 = lane & 15, g = lane >> 4;
  const int m0 = blockIdx.x*64 + wv*16;
  f32x4 acc[8] = {};
  const u16* ar = ao + (size_t)(m0 + r15)*D_ + 4*g;
  #pragma unroll
  for (int kk = 0; kk < D_; kk += 32){
    bf16x8 af = load_frag(ar + kk);
    #pragma unroll
    for (int nf = 0; nf < 8; nf++)
      acc[nf] = __builtin_amdgcn_mfma_f32_16x16x32_bf16(af,
          load_frag(wot + (size_t)(nf*16 + r15)*D_ + kk + 4*g), acc[nf], 0, 0, 0);
  }
  #pragma unroll
  for (int rr = 0; rr < 4; rr++){
    const size_t m = m0 + 4*g + rr;
    float v[8], s1 = 0.f, s2 = 0.f;
    #pragma unroll
    for (int nf = 0; nf < 8; nf++){
      int col = nf*16 + r15;
      float t = acc[nf][rr] + bo[col] + x[m*D_ + col];
      v[nf] = t; s1 += t; s2 += t*t;
    }
    #pragma unroll
    for (int d = 1; d < 16; d <<= 1){ s1 += __shfl_xor(s1, d); s2 += __shfl_xor(s2, d); }
    float mu = s1 * (1.f/D_);
    float var = fmaxf(s2 * (1.f/D_) - mu*mu, 0.f);
    float inv = rsqrtf(var + 1e-5f);
    #pragma unroll
    for (int nf = 0; nf < 8; nf++){
      int col = nf*16 + r15;
      float o = (v[nf]-mu)*inv*g1[col] + be1[col];
      y32[m*D_ + col] = o;
      yb[m*D_ + col] = f2bf(o);
    }
  }
}

// FF1 + exact GELU. grid 1024 (16 rows), 4 waves x 64 cols.
__global__ __launch_bounds__(256) void k_ff1(const u16* yb, const u16* w1t, const float* bf1, u16* hb){
  const int wv = threadIdx.x >> 6, lane = threadIdx.x & 63;
  const int r15 = lane & 15, g = lane >> 4;
  const int m0 = blockIdx.x*16;
  const int n0w = wv*64;
  f32x4 acc[4] = {};
  const u16* ar = yb + (size_t)(m0 + r15)*D_ + 4*g;
  #pragma unroll
  for (int kk = 0; kk < D_; kk += 32){
    bf16x8 af = load_frag(ar + kk);
    #pragma unroll
    for (int nf = 0; nf < 4; nf++)
      acc[nf] = __builtin_amdgcn_mfma_f32_16x16x32_bf16(af,
          load_frag(w1t + (size_t)(n0w + nf*16 + r15)*D_ + kk + 4*g), acc[nf], 0, 0, 0);
  }
  #pragma unroll
  for (int nf = 0; nf < 4; nf++){
    int col = n0w + nf*16 + r15;
    float bias = bf1[col];
    #pragma unroll
    for (int rr = 0; rr < 4; rr++){
      float vv = acc[nf][rr] + bias;
      float gl = 0.5f*vv*(1.f + erff(vv*0.70710678118654752f));
      hb[(size_t)(m0 + 4*g + rr)*FF_ + col] = f2bf(gl);
    }
  }
}

// FF2 + residual + LN2 -> d_out (fp32). grid 256, 64 rows/block.
__global__ __launch_bounds__(256) void k_ff2_ln2(const u16* hb, const u16* w2t, const float* b2,
    const float* y32, const float* g2, const float* be2, float* out){
  const int wv = threadIdx.x >> 6, lane = threadIdx.x & 63;
  const int r15 = lane & 15, g = lane >> 4;
  const int m0 = blockIdx.x*64 + wv*16;
  f32x4 acc[8] = {};
  const u16* ar = hb + (size_t)(m0 + r15)*FF_ + 4*g;
  #pragma unroll
  for (int kk = 0; kk < FF_; kk += 32){
    bf16x8 af = load_frag(ar + kk);
    #pragma unroll
    for (int nf = 0; nf < 8; nf++)
      acc[nf] = __builtin_amdgcn_mfma_f32_16x16x32_bf16(af,
          load_frag(w2t + (size_t)(nf*16 + r15)*FF_ + kk + 4*g), acc[nf], 0, 0, 0);
  }
  #pragma unroll
  for (int rr = 0; rr < 4; rr++){
    const size_t m = m0 + 4*g + rr;
    float v[8], s1 = 0.f, s2 = 0.f;
    #pragma unroll
    for (int nf = 0; nf < 8; nf++){
      int col = nf*16 + r15;
      float t = acc[nf][rr] + b2[col] + y32[m*D_ + col];
      v[nf] = t; s1 += t; s2 += t*t;
    }
    #pragma unroll
    for (int d = 1; d < 16; d <<= 1){ s1 += __shfl_xor(s1, d); s2 += __shfl_xor(s2, d); }
    float mu = s1 * (1.f/D_);
    float var = fmaxf(s2 * (1.f/D_) - mu*mu, 0.f);
    float inv = rsqrtf(var + 1e-5f);
    #pragma unroll
    for (int nf = 0; nf < 8; nf++){
      int col = nf*16 + r15;
      out[m*D_ + col] = (v[nf]-mu)*inv*g2[col] + be2[col];
    }
  }
}

extern "C" void kernel_launch(void* const* d_in, const int* in_sizes, int n_in,
                              void* d_out, int out_size, void* d_ws, size_t ws_size,
                              hipStream_t stream){
  const float* x   = (const float*)d_in[0];
  const void*  msk = d_in[1];
  const float* Wq = (const float*)d_in[2];  const float* bq  = (const float*)d_in[3];
  const float* Wk = (const float*)d_in[4];  const float* bk  = (const float*)d_in[5];
  const float* Wv = (const float*)d_in[6];  const float* bv  = (const float*)d_in[7];
  const float* Wo = (const float*)d_in[8];  const float* bo  = (const float*)d_in[9];
  const float* g1 = (const float*)d_in[10]; const float* be1 = (const float*)d_in[11];
  const float* W1 = (const float*)d_in[12]; const float* bf1 = (const float*)d_in[13];
  const float* W2 = (const float*)d_in[14]; const float* b2  = (const float*)d_in[15];
  const float* g2 = (const float*)d_in[16]; const float* be2 = (const float*)d_in[17];

  char* ws = (char*)d_ws;
  int*      flag  = (int*)     (ws + OFF_FLAG);
  float*    kmax2 = (float*)   (ws + OFF_FLAG + 64);
  unsigned* mw    = (unsigned*)(ws + OFF_MASKW);
  u16* xb    = (u16*)(ws + OFF_XB);
  u16* wqkvt = (u16*)(ws + OFF_WQKVT);
  u16* wot   = (u16*)(ws + OFF_WOT);
  u16* w1t   = (u16*)(ws + OFF_W1T);
  u16* w2t   = (u16*)(ws + OFF_W2T);
  u16* qw    = (u16*)(ws + OFF_QW);
  u16* kw    = (u16*)(ws + OFF_KW);
  u16* vt    = (u16*)(ws + OFF_VT);
  u16* ao    = (u16*)(ws + OFF_AO);
  float* y32 = (float*)(ws + OFF_Y32);
  u16* yb    = (u16*)(ws + OFF_YB);
  u16* hb    = (u16*)(ws + OFF_HB);

  k_detect<<<1, 256, 0, stream>>>((const unsigned*)msk, flag, kmax2);
  k_pack  <<<(T_*T_/32)/256, 256, 0, stream>>>(msk, flag, mw);
  k_conv_x<<<(M_*D_/4)/256, 256, 0, stream>>>(x, xb);
  k_conv_w<<<131072/256, 256, 0, stream>>>(Wq, Wk, Wv, Wo, W1, W2, wqkvt, wot, w1t, w2t);
  k_qkv   <<<M_/16, 256, 0, stream>>>(xb, wqkvt, bq, bk, bv, qw, kw, vt);
  k_knorm <<<B_*H_, 256, 0, stream>>>(kw, kmax2);
  k_attn10<<<(B_*H_)*(T_/64), 256, 0, stream>>>(qw, kw, vt, mw, kmax2, ao);
  k_proj_ln1<<<M_/64, 256, 0, stream>>>(ao, wot, bo, x, g1, be1, y32, yb);
  k_ff1   <<<M_/16, 256, 0, stream>>>(yb, w1t, bf1, hb);
  k_ff2_ln2<<<M_/64, 256, 0, stream>>>(hb, w2t, b2, y32, g2, be2, (float*)d_out);
}